// Round 6
// baseline (944.620 us; speedup 1.0000x reference)
//
#include <hip/hip_runtime.h>

#define BN_EPS 1e-5f

typedef __attribute__((ext_vector_type(8))) short bf16x8;
typedef __attribute__((ext_vector_type(4))) float f32x4;

union VU {
    uint4 u;
    bf16x8 b;
};

// ---------------- CSR build ----------------

__global__ __launch_bounds__(256) void count_k(const int* __restrict__ dst, int E, int* __restrict__ cnt) {
    int i = blockIdx.x * 256 + threadIdx.x;
    if (i < E) atomicAdd(&cnt[dst[i]], 1);
}

__global__ __launch_bounds__(1024) void scan1_k(const int* __restrict__ cnt, int n, int* __restrict__ bsum) {
    __shared__ int sh[1024];
    int i = blockIdx.x * 1024 + threadIdx.x;
    sh[threadIdx.x] = (i < n) ? cnt[i] : 0;
    __syncthreads();
    for (int s = 512; s > 0; s >>= 1) {
        if (threadIdx.x < (unsigned)s) sh[threadIdx.x] += sh[threadIdx.x + s];
        __syncthreads();
    }
    if (threadIdx.x == 0) bsum[blockIdx.x] = sh[0];
}

__global__ void scan2_k(int* bsum, int nb, int* rowptr, int n, int E) {
    if (threadIdx.x == 0 && blockIdx.x == 0) {
        int run = 0;
        for (int i = 0; i < nb; ++i) { int v = bsum[i]; bsum[i] = run; run += v; }
        rowptr[n] = E;
    }
}

__global__ __launch_bounds__(1024) void scan3_k(const int* __restrict__ cnt, int n, const int* __restrict__ boff,
                                                int* __restrict__ rowptr, int* __restrict__ nxt) {
    __shared__ int sh[1024];
    int i = blockIdx.x * 1024 + threadIdx.x;
    int v = (i < n) ? cnt[i] : 0;
    sh[threadIdx.x] = v;
    __syncthreads();
    for (int s = 1; s < 1024; s <<= 1) {
        int t = (threadIdx.x >= (unsigned)s) ? sh[threadIdx.x - s] : 0;
        __syncthreads();
        sh[threadIdx.x] += t;
        __syncthreads();
    }
    if (i < n) {
        int ex = boff[blockIdx.x] + sh[threadIdx.x] - v;
        rowptr[i] = ex;
        nxt[i] = ex;
    }
}

__global__ __launch_bounds__(256) void scatter_k(const int* __restrict__ src, const int* __restrict__ dst, int E,
                                                 int* __restrict__ nxt, int* __restrict__ ssrc) {
    int i = blockIdx.x * 256 + threadIdx.x;
    if (i < E) {
        int d = dst[i];
        int p = atomicAdd(&nxt[d], 1);
        ssrc[p] = src[i];
    }
}

// ---------------- helpers ----------------

static __device__ __forceinline__ unsigned short f2bf(float f) {
    unsigned u = __float_as_uint(f);
    unsigned r = (u + 0x7FFFu + ((u >> 16) & 1u)) >> 16;  // RNE
    return (unsigned short)r;
}
static __device__ __forceinline__ float bf_lo(unsigned u) { return __uint_as_float(u << 16); }
static __device__ __forceinline__ float bf_hi(unsigned u) { return __uint_as_float(u & 0xFFFF0000u); }

// ---------------- prep: pack W (3 layers f32 128x128) into bf16 MFMA A-operand fragments ----------------
// Wp[L][kt][nt][lane] (uint4 = 8 bf16): W[L][k = kt*32 + (lane>>4)*8 + j][n = nt*16 + (lane&15)]

__global__ __launch_bounds__(256) void prepw_k(const float* __restrict__ Ws, uint4* __restrict__ Wp) {
    int id = blockIdx.x * 256 + threadIdx.x;
    if (id >= 3 * 4 * 8 * 64) return;
    int lane = id & 63;
    int nt = (id >> 6) & 7;
    int kt = (id >> 9) & 3;
    int L = id >> 11;
    int quad = lane >> 4, l16 = lane & 15;
    const float* wsrc = Ws + L * 16384 + (kt * 32 + quad * 8) * 128 + nt * 16 + l16;
    unsigned short s[8];
#pragma unroll
    for (int j = 0; j < 8; ++j) s[j] = f2bf(wsrc[j * 128]);
    uint4 pk;
    pk.x = (unsigned)s[0] | ((unsigned)s[1] << 16);
    pk.y = (unsigned)s[2] | ((unsigned)s[3] << 16);
    pk.z = (unsigned)s[4] | ((unsigned)s[5] << 16);
    pk.w = (unsigned)s[6] | ((unsigned)s[7] << 16);
    Wp[id] = pk;
}

// ---------------- MFMA GEMM: H(bf16) = f(X) @ Wp ----------------
// MODE 0: X = f32, f = identity (cvt fused).  MODE 1: X = bf16, f = BN+ReLU (fused at A-load).
// Wave-per-16-row-tile, grid-strided; W resident in 128 VGPRs; no LDS, no barriers.
// mfma(Wfrag, Xfrag, acc) -> (X@W)^T: C col=lane&15 -> H row, C row=quad*4+r -> H col.

template <int MODE>
__global__ __launch_bounds__(256) void mgemm_k(const float* __restrict__ Xf, const unsigned short* __restrict__ Xb,
                                               const uint4* __restrict__ Wp, unsigned short* __restrict__ H,
                                               const float* __restrict__ ss, int n) {
    int lane = threadIdx.x & 63;
    int quad = lane >> 4, l16 = lane & 15;
    int wid = (blockIdx.x * 256 + threadIdx.x) >> 6;
    int nw = (gridDim.x * 256) >> 6;
    int ntiles = (n + 15) >> 4;

    VU b[4][8];
#pragma unroll
    for (int kt = 0; kt < 4; ++kt)
#pragma unroll
        for (int nt = 0; nt < 8; ++nt) b[kt][nt].u = Wp[(kt * 8 + nt) * 64 + lane];

    auto loadA = [&](int tile, VU* a) {
        int row = tile * 16 + l16;
#pragma unroll
        for (int kt = 0; kt < 4; ++kt) {
            float f[8];
            if (MODE == 0) {
                const float* xr = Xf + (size_t)row * 128 + kt * 32 + quad * 8;
                float4 u0 = *(const float4*)(xr);
                float4 u1 = *(const float4*)(xr + 4);
                f[0] = u0.x; f[1] = u0.y; f[2] = u0.z; f[3] = u0.w;
                f[4] = u1.x; f[5] = u1.y; f[6] = u1.z; f[7] = u1.w;
            } else {
                uint4 u = *(const uint4*)(Xb + (size_t)row * 128 + kt * 32 + quad * 8);
                f[0] = bf_lo(u.x); f[1] = bf_hi(u.x); f[2] = bf_lo(u.y); f[3] = bf_hi(u.y);
                f[4] = bf_lo(u.z); f[5] = bf_hi(u.z); f[6] = bf_lo(u.w); f[7] = bf_hi(u.w);
                const float4* scp = (const float4*)(ss + kt * 32 + quad * 8);
                const float4* shp = (const float4*)(ss + 128 + kt * 32 + quad * 8);
                float4 c0 = scp[0], c1 = scp[1], d0 = shp[0], d1 = shp[1];
                f[0] = fmaxf(fmaf(f[0], c0.x, d0.x), 0.f);
                f[1] = fmaxf(fmaf(f[1], c0.y, d0.y), 0.f);
                f[2] = fmaxf(fmaf(f[2], c0.z, d0.z), 0.f);
                f[3] = fmaxf(fmaf(f[3], c0.w, d0.w), 0.f);
                f[4] = fmaxf(fmaf(f[4], c1.x, d1.x), 0.f);
                f[5] = fmaxf(fmaf(f[5], c1.y, d1.y), 0.f);
                f[6] = fmaxf(fmaf(f[6], c1.z, d1.z), 0.f);
                f[7] = fmaxf(fmaf(f[7], c1.w, d1.w), 0.f);
            }
            uint4 pk;
            pk.x = (unsigned)f2bf(f[0]) | ((unsigned)f2bf(f[1]) << 16);
            pk.y = (unsigned)f2bf(f[2]) | ((unsigned)f2bf(f[3]) << 16);
            pk.z = (unsigned)f2bf(f[4]) | ((unsigned)f2bf(f[5]) << 16);
            pk.w = (unsigned)f2bf(f[6]) | ((unsigned)f2bf(f[7]) << 16);
            a[kt].u = pk;
        }
    };

    int t = wid;
    VU a[4];
    if (t < ntiles) loadA(t, a);

    while (t < ntiles) {
        int tn = t + nw;
        VU an[4];
        if (tn < ntiles) loadA(tn, an);

        f32x4 acc[8];
#pragma unroll
        for (int nt = 0; nt < 8; ++nt) acc[nt] = (f32x4){0.f, 0.f, 0.f, 0.f};
#pragma unroll
        for (int kt = 0; kt < 4; ++kt)
#pragma unroll
            for (int nt = 0; nt < 8; ++nt)
                acc[nt] = __builtin_amdgcn_mfma_f32_16x16x32_bf16(b[kt][nt].b, a[kt].b, acc[nt], 0, 0, 0);

        unsigned short* hp = H + (size_t)(t * 16 + l16) * 128 + quad * 4;
#pragma unroll
        for (int nt = 0; nt < 8; ++nt) {
            uint2 pk;
            pk.x = (unsigned)f2bf(acc[nt][0]) | ((unsigned)f2bf(acc[nt][1]) << 16);
            pk.y = (unsigned)f2bf(acc[nt][2]) | ((unsigned)f2bf(acc[nt][3]) << 16);
            *(uint2*)(hp + nt * 16) = pk;
        }

#pragma unroll
        for (int kt = 0; kt < 4; ++kt) a[kt] = an[kt];
        t = tn;
    }
}

// ---------------- Aggregation: wave per node; HALF-wave (32 lanes, uint2 = 4 feats) per edge ----------------
// One gather instruction covers 2 edges (512 B). Branch-free; 16-edge unroll = 8 instructions in flight.
// MODE 0: write bf16 + f32 BN stats via LDS pre-reduce + float atomics.  MODE 1: fused log_softmax.

template <int MODE>
__global__ __launch_bounds__(256) void agg_k(const unsigned short* __restrict__ H, const int* __restrict__ rowptr,
                                             const int* __restrict__ ssrc, unsigned* __restrict__ outb,
                                             float* __restrict__ outf, float* __restrict__ stats, int n) {
    __shared__ float sred[4][8][64];
    int lane = threadIdx.x & 63;
    int half = lane >> 5;      // which edge of the pair
    int l32 = lane & 31;       // feature group: cols l32*4 .. l32*4+3
    int wv = threadIdx.x >> 6;
    int wid = (blockIdx.x * 256 + threadIdx.x) >> 6;
    int nw = (gridDim.x * 256) >> 6;
    const unsigned short* hb = H + 4 * l32;
    float s0 = 0, s1 = 0, s2 = 0, s3 = 0, q0 = 0, q1 = 0, q2 = 0, q3 = 0;

    for (int node = wid; node < n; node += nw) {
        int beg = rowptr[node], end = rowptr[node + 1];
        float a0 = 0.f, a1 = 0.f, a2 = 0.f, a3 = 0.f;
        int e = beg;
        for (; e + 16 <= end; e += 16) {
            int j0 = half ? ssrc[e + 1] : ssrc[e + 0];
            int j1 = half ? ssrc[e + 3] : ssrc[e + 2];
            int j2 = half ? ssrc[e + 5] : ssrc[e + 4];
            int j3 = half ? ssrc[e + 7] : ssrc[e + 6];
            int j4 = half ? ssrc[e + 9] : ssrc[e + 8];
            int j5 = half ? ssrc[e + 11] : ssrc[e + 10];
            int j6 = half ? ssrc[e + 13] : ssrc[e + 12];
            int j7 = half ? ssrc[e + 15] : ssrc[e + 14];
            uint2 v0 = *(const uint2*)(hb + (size_t)j0 * 128);
            uint2 v1 = *(const uint2*)(hb + (size_t)j1 * 128);
            uint2 v2 = *(const uint2*)(hb + (size_t)j2 * 128);
            uint2 v3 = *(const uint2*)(hb + (size_t)j3 * 128);
            uint2 v4 = *(const uint2*)(hb + (size_t)j4 * 128);
            uint2 v5 = *(const uint2*)(hb + (size_t)j5 * 128);
            uint2 v6 = *(const uint2*)(hb + (size_t)j6 * 128);
            uint2 v7 = *(const uint2*)(hb + (size_t)j7 * 128);
            a0 += ((bf_lo(v0.x) + bf_lo(v1.x)) + (bf_lo(v2.x) + bf_lo(v3.x))) +
                  ((bf_lo(v4.x) + bf_lo(v5.x)) + (bf_lo(v6.x) + bf_lo(v7.x)));
            a1 += ((bf_hi(v0.x) + bf_hi(v1.x)) + (bf_hi(v2.x) + bf_hi(v3.x))) +
                  ((bf_hi(v4.x) + bf_hi(v5.x)) + (bf_hi(v6.x) + bf_hi(v7.x)));
            a2 += ((bf_lo(v0.y) + bf_lo(v1.y)) + (bf_lo(v2.y) + bf_lo(v3.y))) +
                  ((bf_lo(v4.y) + bf_lo(v5.y)) + (bf_lo(v6.y) + bf_lo(v7.y)));
            a3 += ((bf_hi(v0.y) + bf_hi(v1.y)) + (bf_hi(v2.y) + bf_hi(v3.y))) +
                  ((bf_hi(v4.y) + bf_hi(v5.y)) + (bf_hi(v6.y) + bf_hi(v7.y)));
        }
        if (e + 8 <= end) {
            int j0 = half ? ssrc[e + 1] : ssrc[e + 0];
            int j1 = half ? ssrc[e + 3] : ssrc[e + 2];
            int j2 = half ? ssrc[e + 5] : ssrc[e + 4];
            int j3 = half ? ssrc[e + 7] : ssrc[e + 6];
            uint2 v0 = *(const uint2*)(hb + (size_t)j0 * 128);
            uint2 v1 = *(const uint2*)(hb + (size_t)j1 * 128);
            uint2 v2 = *(const uint2*)(hb + (size_t)j2 * 128);
            uint2 v3 = *(const uint2*)(hb + (size_t)j3 * 128);
            a0 += (bf_lo(v0.x) + bf_lo(v1.x)) + (bf_lo(v2.x) + bf_lo(v3.x));
            a1 += (bf_hi(v0.x) + bf_hi(v1.x)) + (bf_hi(v2.x) + bf_hi(v3.x));
            a2 += (bf_lo(v0.y) + bf_lo(v1.y)) + (bf_lo(v2.y) + bf_lo(v3.y));
            a3 += (bf_hi(v0.y) + bf_hi(v1.y)) + (bf_hi(v2.y) + bf_hi(v3.y));
            e += 8;
        }
        for (; e < end; e += 2) {
            int iE = ssrc[e];
            int iO = (e + 1 < end) ? ssrc[e + 1] : iE;
            int j = half ? iO : iE;
            uint2 v = *(const uint2*)(hb + (size_t)j * 128);
            float wsc = (half && (e + 1 >= end)) ? 0.f : 1.f;  // kill duplicate on odd tail
            a0 += wsc * bf_lo(v.x);
            a1 += wsc * bf_hi(v.x);
            a2 += wsc * bf_lo(v.y);
            a3 += wsc * bf_hi(v.y);
        }

        // combine the two halves: lanes l and l^32 hold partials of the same 4 feats
        a0 += __shfl_xor(a0, 32);
        a1 += __shfl_xor(a1, 32);
        a2 += __shfl_xor(a2, 32);
        a3 += __shfl_xor(a3, 32);

        if (MODE == 0) {
            if (half == 0) {
                uint2 pk;
                pk.x = (unsigned)f2bf(a0) | ((unsigned)f2bf(a1) << 16);
                pk.y = (unsigned)f2bf(a2) | ((unsigned)f2bf(a3) << 16);
                *(uint2*)(outb + (size_t)node * 64 + l32 * 2) = pk;
            }
            s0 += a0; q0 += a0 * a0;
            s1 += a1; q1 += a1 * a1;
            s2 += a2; q2 += a2 * a2;
            s3 += a3; q3 += a3 * a3;
        } else {
            float m = fmaxf(fmaxf(a0, a1), fmaxf(a2, a3));
            m = fmaxf(m, __shfl_xor(m, 1));
            m = fmaxf(m, __shfl_xor(m, 2));
            m = fmaxf(m, __shfl_xor(m, 4));
            m = fmaxf(m, __shfl_xor(m, 8));
            m = fmaxf(m, __shfl_xor(m, 16));
            float ex = (expf(a0 - m) + expf(a1 - m)) + (expf(a2 - m) + expf(a3 - m));
            ex += __shfl_xor(ex, 1);
            ex += __shfl_xor(ex, 2);
            ex += __shfl_xor(ex, 4);
            ex += __shfl_xor(ex, 8);
            ex += __shfl_xor(ex, 16);
            float lse = m + logf(ex);
            if (half == 0)
                *(float4*)(outf + (size_t)node * 128 + l32 * 4) = make_float4(a0 - lse, a1 - lse, a2 - lse, a3 - lse);
        }
    }

    if (MODE == 0) {
        // both halves hold identical totals; only half 0 is used after the cross-wave reduce
        sred[wv][0][lane] = s0;
        sred[wv][1][lane] = s1;
        sred[wv][2][lane] = s2;
        sred[wv][3][lane] = s3;
        sred[wv][4][lane] = q0;
        sred[wv][5][lane] = q1;
        sred[wv][6][lane] = q2;
        sred[wv][7][lane] = q3;
        __syncthreads();
        if (wv == 0 && half == 0) {
#pragma unroll
            for (int j = 0; j < 4; ++j) {
                float ts = (sred[0][j][lane] + sred[1][j][lane]) + (sred[2][j][lane] + sred[3][j][lane]);
                float tq = (sred[0][4 + j][lane] + sred[1][4 + j][lane]) + (sred[2][4 + j][lane] + sred[3][4 + j][lane]);
                atomicAdd(&stats[l32 * 4 + j], ts);
                atomicAdd(&stats[128 + l32 * 4 + j], tq);
            }
        }
    }
}

// ---------------- BN finalize ----------------

__global__ void bnfin_k(const float* __restrict__ stats, const float* __restrict__ gamma,
                        const float* __restrict__ beta, float* __restrict__ ss, int n) {
    int f = threadIdx.x;
    if (f < 128) {
        float mu = stats[f] / n;
        float var = stats[128 + f] / n - mu * mu;
        float rs = rsqrtf(fmaxf(var, 0.f) + BN_EPS);
        float sc = gamma[f] * rs;
        ss[f] = sc;
        ss[128 + f] = beta[f] - mu * sc;
    }
}

// ---------------- driver ----------------

extern "C" void kernel_launch(void* const* d_in, const int* in_sizes, int n_in,
                              void* d_out, int out_size, void* d_ws, size_t ws_size,
                              hipStream_t stream) {
    const float* x = (const float*)d_in[0];
    const int* ei = (const int*)d_in[1];
    const float* Ws = (const float*)d_in[2];
    const float* gammas = (const float*)d_in[3];
    const float* betas = (const float*)d_in[4];
    int N = in_sizes[0] / 128;
    int E = in_sizes[1] / 2;
    const int* src = ei;
    const int* dst = ei + E;
    float* out = (float*)d_out;

    char* w = (char*)d_ws;
    size_t o = 0;
    auto alloc = [&](size_t bytes) { char* p = w + o; o += (bytes + 511) & ~511ull; return p; };
    unsigned short* h = (unsigned short*)alloc((size_t)N * 128 * 2);   // bf16 GEMM out / agg in
    unsigned short* h2 = (unsigned short*)alloc((size_t)N * 128 * 2);  // bf16 agg out / GEMM in
    int* cnt = (int*)alloc((size_t)N * 4);
    int* rowptr = (int*)alloc(((size_t)N + 1) * 4);
    int* nxt = (int*)alloc((size_t)N * 4);
    int* bsum = (int*)alloc(4096);
    int* ssrc = (int*)alloc((size_t)E * 4);
    uint4* Wp = (uint4*)alloc(3 * 2048 * 16);  // packed bf16 W fragments
    float* stats = (float*)alloc(512 * 4);
    float* ss = (float*)alloc(512 * 4);

    hipMemsetAsync(cnt, 0, (size_t)N * 4, stream);
    hipMemsetAsync(stats, 0, 512 * 4, stream);

    int ebl = (E + 255) / 256;
    int nb = (N + 1023) / 1024;
    prepw_k<<<24, 256, 0, stream>>>(Ws, Wp);
    count_k<<<ebl, 256, 0, stream>>>(dst, E, cnt);
    scan1_k<<<nb, 1024, 0, stream>>>(cnt, N, bsum);
    scan2_k<<<1, 64, 0, stream>>>(bsum, nb, rowptr, N, E);
    scan3_k<<<nb, 1024, 0, stream>>>(cnt, N, bsum, rowptr, nxt);
    scatter_k<<<ebl, 256, 0, stream>>>(src, dst, E, nxt, ssrc);

    const int AGG_BLOCKS = 2048;
    const int GEMM_BLOCKS = 512;

    mgemm_k<0><<<GEMM_BLOCKS, 256, 0, stream>>>(x, nullptr, Wp, h, nullptr, N);
    agg_k<0><<<AGG_BLOCKS, 256, 0, stream>>>(h, rowptr, ssrc, (unsigned*)h2, nullptr, stats, N);
    bnfin_k<<<1, 128, 0, stream>>>(stats, gammas, betas, ss, N);
    mgemm_k<1><<<GEMM_BLOCKS, 256, 0, stream>>>(nullptr, h2, Wp + 2048, h, ss, N);
    agg_k<0><<<AGG_BLOCKS, 256, 0, stream>>>(h, rowptr, ssrc, (unsigned*)h2, nullptr, stats + 256, N);
    bnfin_k<<<1, 128, 0, stream>>>(stats + 256, gammas + 128, betas + 128, ss + 256, N);
    mgemm_k<1><<<GEMM_BLOCKS, 256, 0, stream>>>(nullptr, h2, Wp + 4096, h, ss + 256, N);
    agg_k<1><<<AGG_BLOCKS, 256, 0, stream>>>(h, rowptr, ssrc, nullptr, out, nullptr, N);
}

// Round 7
// 770.930 us; speedup vs baseline: 1.2253x; 1.2253x over previous
//
#include <hip/hip_runtime.h>

#define BN_EPS 1e-5f

typedef __attribute__((ext_vector_type(8))) short bf16x8;
typedef __attribute__((ext_vector_type(4))) float f32x4;

union VU {
    uint4 u;
    bf16x8 b;
};

// ---------------- CSR build ----------------

__global__ __launch_bounds__(256) void count_k(const int* __restrict__ dst, int E, int* __restrict__ cnt) {
    int i = blockIdx.x * 256 + threadIdx.x;
    if (i < E) atomicAdd(&cnt[dst[i]], 1);
}

__global__ __launch_bounds__(1024) void scan1_k(const int* __restrict__ cnt, int n, int* __restrict__ bsum) {
    __shared__ int sh[1024];
    int i = blockIdx.x * 1024 + threadIdx.x;
    sh[threadIdx.x] = (i < n) ? cnt[i] : 0;
    __syncthreads();
    for (int s = 512; s > 0; s >>= 1) {
        if (threadIdx.x < (unsigned)s) sh[threadIdx.x] += sh[threadIdx.x + s];
        __syncthreads();
    }
    if (threadIdx.x == 0) bsum[blockIdx.x] = sh[0];
}

__global__ void scan2_k(int* bsum, int nb, int* rowptr, int n, int E) {
    if (threadIdx.x == 0 && blockIdx.x == 0) {
        int run = 0;
        for (int i = 0; i < nb; ++i) { int v = bsum[i]; bsum[i] = run; run += v; }
        rowptr[n] = E;
    }
}

__global__ __launch_bounds__(1024) void scan3_k(const int* __restrict__ cnt, int n, const int* __restrict__ boff,
                                                int* __restrict__ rowptr, int* __restrict__ nxt) {
    __shared__ int sh[1024];
    int i = blockIdx.x * 1024 + threadIdx.x;
    int v = (i < n) ? cnt[i] : 0;
    sh[threadIdx.x] = v;
    __syncthreads();
    for (int s = 1; s < 1024; s <<= 1) {
        int t = (threadIdx.x >= (unsigned)s) ? sh[threadIdx.x - s] : 0;
        __syncthreads();
        sh[threadIdx.x] += t;
        __syncthreads();
    }
    if (i < n) {
        int ex = boff[blockIdx.x] + sh[threadIdx.x] - v;
        rowptr[i] = ex;
        nxt[i] = ex;
    }
}

__global__ __launch_bounds__(256) void scatter_k(const int* __restrict__ src, const int* __restrict__ dst, int E,
                                                 int* __restrict__ nxt, int* __restrict__ ssrc) {
    int i = blockIdx.x * 256 + threadIdx.x;
    if (i < E) {
        int d = dst[i];
        int p = atomicAdd(&nxt[d], 1);
        ssrc[p] = src[i];
    }
}

// ---------------- helpers ----------------

static __device__ __forceinline__ unsigned short f2bf(float f) {
    unsigned u = __float_as_uint(f);
    unsigned r = (u + 0x7FFFu + ((u >> 16) & 1u)) >> 16;  // RNE
    return (unsigned short)r;
}
static __device__ __forceinline__ float bf_lo(unsigned u) { return __uint_as_float(u << 16); }
static __device__ __forceinline__ float bf_hi(unsigned u) { return __uint_as_float(u & 0xFFFF0000u); }

// ---------------- prep: pack W (3 layers f32 128x128) into bf16 MFMA fragments ----------------
// Wp[L][kt][nt][lane] (uint4 = 8 bf16): W[L][k = kt*32 + (lane>>4)*8 + j][n = nt*16 + (lane&15)]

__global__ __launch_bounds__(256) void prepw_k(const float* __restrict__ Ws, uint4* __restrict__ Wp) {
    int id = blockIdx.x * 256 + threadIdx.x;
    if (id >= 3 * 4 * 8 * 64) return;
    int lane = id & 63;
    int nt = (id >> 6) & 7;
    int kt = (id >> 9) & 3;
    int L = id >> 11;
    int quad = lane >> 4, l16 = lane & 15;
    const float* wsrc = Ws + L * 16384 + (kt * 32 + quad * 8) * 128 + nt * 16 + l16;
    unsigned short s[8];
#pragma unroll
    for (int j = 0; j < 8; ++j) s[j] = f2bf(wsrc[j * 128]);
    uint4 pk;
    pk.x = (unsigned)s[0] | ((unsigned)s[1] << 16);
    pk.y = (unsigned)s[2] | ((unsigned)s[3] << 16);
    pk.z = (unsigned)s[4] | ((unsigned)s[5] << 16);
    pk.w = (unsigned)s[6] | ((unsigned)s[7] << 16);
    Wp[id] = pk;
}

// ---------------- MFMA GEMM: H(bf16) = f(X) @ Wp ----------------
// MODE 0: X = f32, f = identity (cvt fused).  MODE 1: X = bf16, f = BN+ReLU (fused at A-load).
// Wave-per-16-row-tile, grid-strided; W resident in 128 VGPRs; no LDS, no barriers.
// mfma(Wfrag, Xfrag, acc) -> (X@W)^T: C col=lane&15 -> H row, C row=quad*4+r -> H col.

template <int MODE>
__global__ __launch_bounds__(256) void mgemm_k(const float* __restrict__ Xf, const unsigned short* __restrict__ Xb,
                                               const uint4* __restrict__ Wp, unsigned short* __restrict__ H,
                                               const float* __restrict__ ss, int n) {
    int lane = threadIdx.x & 63;
    int quad = lane >> 4, l16 = lane & 15;
    int wid = (blockIdx.x * 256 + threadIdx.x) >> 6;
    int nw = (gridDim.x * 256) >> 6;
    int ntiles = (n + 15) >> 4;

    VU b[4][8];
#pragma unroll
    for (int kt = 0; kt < 4; ++kt)
#pragma unroll
        for (int nt = 0; nt < 8; ++nt) b[kt][nt].u = Wp[(kt * 8 + nt) * 64 + lane];

    auto loadA = [&](int tile, VU* a) {
        int row = tile * 16 + l16;
#pragma unroll
        for (int kt = 0; kt < 4; ++kt) {
            float f[8];
            if (MODE == 0) {
                const float* xr = Xf + (size_t)row * 128 + kt * 32 + quad * 8;
                float4 u0 = *(const float4*)(xr);
                float4 u1 = *(const float4*)(xr + 4);
                f[0] = u0.x; f[1] = u0.y; f[2] = u0.z; f[3] = u0.w;
                f[4] = u1.x; f[5] = u1.y; f[6] = u1.z; f[7] = u1.w;
            } else {
                uint4 u = *(const uint4*)(Xb + (size_t)row * 128 + kt * 32 + quad * 8);
                f[0] = bf_lo(u.x); f[1] = bf_hi(u.x); f[2] = bf_lo(u.y); f[3] = bf_hi(u.y);
                f[4] = bf_lo(u.z); f[5] = bf_hi(u.z); f[6] = bf_lo(u.w); f[7] = bf_hi(u.w);
                const float4* scp = (const float4*)(ss + kt * 32 + quad * 8);
                const float4* shp = (const float4*)(ss + 128 + kt * 32 + quad * 8);
                float4 c0 = scp[0], c1 = scp[1], d0 = shp[0], d1 = shp[1];
                f[0] = fmaxf(fmaf(f[0], c0.x, d0.x), 0.f);
                f[1] = fmaxf(fmaf(f[1], c0.y, d0.y), 0.f);
                f[2] = fmaxf(fmaf(f[2], c0.z, d0.z), 0.f);
                f[3] = fmaxf(fmaf(f[3], c0.w, d0.w), 0.f);
                f[4] = fmaxf(fmaf(f[4], c1.x, d1.x), 0.f);
                f[5] = fmaxf(fmaf(f[5], c1.y, d1.y), 0.f);
                f[6] = fmaxf(fmaf(f[6], c1.z, d1.z), 0.f);
                f[7] = fmaxf(fmaf(f[7], c1.w, d1.w), 0.f);
            }
            uint4 pk;
            pk.x = (unsigned)f2bf(f[0]) | ((unsigned)f2bf(f[1]) << 16);
            pk.y = (unsigned)f2bf(f[2]) | ((unsigned)f2bf(f[3]) << 16);
            pk.z = (unsigned)f2bf(f[4]) | ((unsigned)f2bf(f[5]) << 16);
            pk.w = (unsigned)f2bf(f[6]) | ((unsigned)f2bf(f[7]) << 16);
            a[kt].u = pk;
        }
    };

    int t = wid;
    VU a[4];
    if (t < ntiles) loadA(t, a);

    while (t < ntiles) {
        int tn = t + nw;
        VU an[4];
        if (tn < ntiles) loadA(tn, an);

        f32x4 acc[8];
#pragma unroll
        for (int nt = 0; nt < 8; ++nt) acc[nt] = (f32x4){0.f, 0.f, 0.f, 0.f};
#pragma unroll
        for (int kt = 0; kt < 4; ++kt)
#pragma unroll
            for (int nt = 0; nt < 8; ++nt)
                acc[nt] = __builtin_amdgcn_mfma_f32_16x16x32_bf16(b[kt][nt].b, a[kt].b, acc[nt], 0, 0, 0);

        unsigned short* hp = H + (size_t)(t * 16 + l16) * 128 + quad * 4;
#pragma unroll
        for (int nt = 0; nt < 8; ++nt) {
            uint2 pk;
            pk.x = (unsigned)f2bf(acc[nt][0]) | ((unsigned)f2bf(acc[nt][1]) << 16);
            pk.y = (unsigned)f2bf(acc[nt][2]) | ((unsigned)f2bf(acc[nt][3]) << 16);
            *(uint2*)(hp + nt * 16) = pk;
        }

#pragma unroll
        for (int kt = 0; kt < 4; ++kt) a[kt] = an[kt];
        t = tn;
    }
}

// ---------------- Aggregation: wave per node, lane reads 2 bf16 feats (one unsigned) per edge ----------------
// R4 structure (one row per instruction, branch-free) with 16-edge flat unroll:
// indices batch-loaded first, then 16 independent gathers in flight.
// MODE 0: write bf16 + f32 BN stats via LDS pre-reduce + float atomics.  MODE 1: fused log_softmax.

template <int MODE>
__global__ __launch_bounds__(256) void agg_k(const unsigned short* __restrict__ H, const int* __restrict__ rowptr,
                                             const int* __restrict__ ssrc, unsigned* __restrict__ outb,
                                             float* __restrict__ outf, float* __restrict__ stats, int n) {
    __shared__ float sred[4][4][64];
    int lane = threadIdx.x & 63;
    int wv = threadIdx.x >> 6;
    int wid = (blockIdx.x * 256 + threadIdx.x) >> 6;
    int nw = (gridDim.x * 256) >> 6;
    const unsigned short* hb = H + 2 * lane;
    float s0 = 0, s1 = 0, q0 = 0, q1 = 0;

    for (int node = wid; node < n; node += nw) {
        int beg = rowptr[node], end = rowptr[node + 1];
        float ax = 0.f, ay = 0.f;
        int e = beg;
        for (; e + 16 <= end; e += 16) {
            int idx[16];
#pragma unroll
            for (int j = 0; j < 16; ++j) idx[j] = ssrc[e + j];
            unsigned v[16];
#pragma unroll
            for (int j = 0; j < 16; ++j) v[j] = *(const unsigned*)(hb + (size_t)idx[j] * 128);
            float lx0 = 0.f, lx1 = 0.f, ly0 = 0.f, ly1 = 0.f;
#pragma unroll
            for (int j = 0; j < 8; ++j) {
                lx0 += bf_lo(v[j]);
                ly0 += bf_hi(v[j]);
                lx1 += bf_lo(v[8 + j]);
                ly1 += bf_hi(v[8 + j]);
            }
            ax += lx0 + lx1;
            ay += ly0 + ly1;
        }
        if (e + 8 <= end) {
            int idx[8];
#pragma unroll
            for (int j = 0; j < 8; ++j) idx[j] = ssrc[e + j];
            unsigned v[8];
#pragma unroll
            for (int j = 0; j < 8; ++j) v[j] = *(const unsigned*)(hb + (size_t)idx[j] * 128);
#pragma unroll
            for (int j = 0; j < 8; ++j) {
                ax += bf_lo(v[j]);
                ay += bf_hi(v[j]);
            }
            e += 8;
        }
        if (e + 4 <= end) {
            int idx[4];
#pragma unroll
            for (int j = 0; j < 4; ++j) idx[j] = ssrc[e + j];
            unsigned v[4];
#pragma unroll
            for (int j = 0; j < 4; ++j) v[j] = *(const unsigned*)(hb + (size_t)idx[j] * 128);
#pragma unroll
            for (int j = 0; j < 4; ++j) {
                ax += bf_lo(v[j]);
                ay += bf_hi(v[j]);
            }
            e += 4;
        }
        for (; e < end; ++e) {
            unsigned v = *(const unsigned*)(hb + (size_t)ssrc[e] * 128);
            ax += bf_lo(v);
            ay += bf_hi(v);
        }

        if (MODE == 0) {
            outb[(size_t)node * 64 + lane] = (unsigned)f2bf(ax) | ((unsigned)f2bf(ay) << 16);
            s0 += ax; q0 += ax * ax;
            s1 += ay; q1 += ay * ay;
        } else {
            float m = fmaxf(ax, ay);
#pragma unroll
            for (int off = 32; off > 0; off >>= 1) m = fmaxf(m, __shfl_xor(m, off));
            float ex = expf(ax - m) + expf(ay - m);
#pragma unroll
            for (int off = 32; off > 0; off >>= 1) ex += __shfl_xor(ex, off);
            float lse = m + logf(ex);
            *(float2*)(outf + (size_t)node * 128 + 2 * lane) = make_float2(ax - lse, ay - lse);
        }
    }

    if (MODE == 0) {
        sred[wv][0][lane] = s0;
        sred[wv][1][lane] = s1;
        sred[wv][2][lane] = q0;
        sred[wv][3][lane] = q1;
        __syncthreads();
        if (wv == 0) {
            float t0 = (sred[0][0][lane] + sred[1][0][lane]) + (sred[2][0][lane] + sred[3][0][lane]);
            float t1 = (sred[0][1][lane] + sred[1][1][lane]) + (sred[2][1][lane] + sred[3][1][lane]);
            float t2 = (sred[0][2][lane] + sred[1][2][lane]) + (sred[2][2][lane] + sred[3][2][lane]);
            float t3 = (sred[0][3][lane] + sred[1][3][lane]) + (sred[2][3][lane] + sred[3][3][lane]);
            atomicAdd(&stats[2 * lane], t0);
            atomicAdd(&stats[2 * lane + 1], t1);
            atomicAdd(&stats[128 + 2 * lane], t2);
            atomicAdd(&stats[128 + 2 * lane + 1], t3);
        }
    }
}

// ---------------- BN finalize ----------------

__global__ void bnfin_k(const float* __restrict__ stats, const float* __restrict__ gamma,
                        const float* __restrict__ beta, float* __restrict__ ss, int n) {
    int f = threadIdx.x;
    if (f < 128) {
        float mu = stats[f] / n;
        float var = stats[128 + f] / n - mu * mu;
        float rs = rsqrtf(fmaxf(var, 0.f) + BN_EPS);
        float sc = gamma[f] * rs;
        ss[f] = sc;
        ss[128 + f] = beta[f] - mu * sc;
    }
}

// ---------------- driver ----------------

extern "C" void kernel_launch(void* const* d_in, const int* in_sizes, int n_in,
                              void* d_out, int out_size, void* d_ws, size_t ws_size,
                              hipStream_t stream) {
    const float* x = (const float*)d_in[0];
    const int* ei = (const int*)d_in[1];
    const float* Ws = (const float*)d_in[2];
    const float* gammas = (const float*)d_in[3];
    const float* betas = (const float*)d_in[4];
    int N = in_sizes[0] / 128;
    int E = in_sizes[1] / 2;
    const int* src = ei;
    const int* dst = ei + E;
    float* out = (float*)d_out;

    char* w = (char*)d_ws;
    size_t o = 0;
    auto alloc = [&](size_t bytes) { char* p = w + o; o += (bytes + 511) & ~511ull; return p; };
    unsigned short* h = (unsigned short*)alloc((size_t)N * 128 * 2);   // bf16 GEMM out / agg in
    unsigned short* h2 = (unsigned short*)alloc((size_t)N * 128 * 2);  // bf16 agg out / GEMM in
    int* cnt = (int*)alloc((size_t)N * 4);
    int* rowptr = (int*)alloc(((size_t)N + 1) * 4);
    int* nxt = (int*)alloc((size_t)N * 4);
    int* bsum = (int*)alloc(4096);
    int* ssrc = (int*)alloc((size_t)E * 4);
    uint4* Wp = (uint4*)alloc(3 * 2048 * 16);  // packed bf16 W fragments
    float* stats = (float*)alloc(512 * 4);
    float* ss = (float*)alloc(512 * 4);

    hipMemsetAsync(cnt, 0, (size_t)N * 4, stream);
    hipMemsetAsync(stats, 0, 512 * 4, stream);

    int ebl = (E + 255) / 256;
    int nb = (N + 1023) / 1024;
    prepw_k<<<24, 256, 0, stream>>>(Ws, Wp);
    count_k<<<ebl, 256, 0, stream>>>(dst, E, cnt);
    scan1_k<<<nb, 1024, 0, stream>>>(cnt, N, bsum);
    scan2_k<<<1, 64, 0, stream>>>(bsum, nb, rowptr, N, E);
    scan3_k<<<nb, 1024, 0, stream>>>(cnt, N, bsum, rowptr, nxt);
    scatter_k<<<ebl, 256, 0, stream>>>(src, dst, E, nxt, ssrc);

    const int AGG_BLOCKS = 2048;
    const int GEMM_BLOCKS = 512;

    mgemm_k<0><<<GEMM_BLOCKS, 256, 0, stream>>>(x, nullptr, Wp, h, nullptr, N);
    agg_k<0><<<AGG_BLOCKS, 256, 0, stream>>>(h, rowptr, ssrc, (unsigned*)h2, nullptr, stats, N);
    bnfin_k<<<1, 128, 0, stream>>>(stats, gammas, betas, ss, N);
    mgemm_k<1><<<GEMM_BLOCKS, 256, 0, stream>>>(nullptr, h2, Wp + 2048, h, ss, N);
    agg_k<0><<<AGG_BLOCKS, 256, 0, stream>>>(h, rowptr, ssrc, (unsigned*)h2, nullptr, stats + 256, N);
    bnfin_k<<<1, 128, 0, stream>>>(stats + 256, gammas + 128, betas + 128, ss + 256, N);
    mgemm_k<1><<<GEMM_BLOCKS, 256, 0, stream>>>(nullptr, h2, Wp + 4096, h, ss + 256, N);
    agg_k<1><<<AGG_BLOCKS, 256, 0, stream>>>(h, rowptr, ssrc, nullptr, out, nullptr, N);
}